// Round 6
// baseline (79.646 us; speedup 1.0000x reference)
//
#include <hip/hip_runtime.h>

typedef __bf16 v8bf __attribute__((ext_vector_type(8)));
typedef float f32x4 __attribute__((ext_vector_type(4)));

#define C_IN 256
#define HW   64
#define OHW  63
#define NOC  128

// Wf: [kp(4)][khkw(4)][cblk(32)][oc(128)][j(8)] bf16, 1 MiB. Coalesced.
__global__ void wprep(const float* __restrict__ w, __bf16* __restrict__ Wf) {
  int f = blockIdx.x;                 // 512 filters
  int c = threadIdx.x;                // 256 channels
  f32x4 v = *(const f32x4*)(w + (size_t)f * 1024 + c * 4);  // 4 khkw taps
  int oc = f >> 2, kp = f & 3;
#pragma unroll
  for (int khkw = 0; khkw < 4; ++khkw)
    Wf[(((size_t)(kp * 4 + khkw) * 32 + (c >> 3)) * 128 + oc) * 8 + (c & 7)] =
        (__bf16)v[khkw];
}

// 512-thr blocks (8 waves), 2 output rows per block, grid (32,16) = 2 blocks/CU.
// wave = ocg(2: 64 oc, m=4 frags) x kp(4).  f=2 px-frags (hh).  acc 4x2 f32x4.
// LDS x tile: [dy(3)][wpair(33)][par(2)][c(32)] bf16, XOR-swizzled, dbuf.
// Per chunk q: A(q)->regs (16 dwordx4, L2) FIRST, then x(q+1) (3 dwordx4),
// compute (no VMEM inside), WRITEQ(q+1), one barrier. Sibling block overlaps.
__global__ __launch_bounds__(512, 4) void robin_main(
    const float* __restrict__ x, const __bf16* __restrict__ Wf,
    const float* __restrict__ bias, float* __restrict__ out) {
  __shared__ __align__(16) __bf16 xs[2][3 * 33 * 64];   // 2 x 12672 B
  char* xb0 = (char*)xs[0];
  char* xb1 = (char*)xs[1];

  const int tid   = threadIdx.x;
  const int lane  = tid & 63;
  const int wid   = tid >> 6;         // 0..7
  const int strip = blockIdx.x;       // 32 strips of 2 output rows
  const int n     = blockIdx.y;       // 16
  const int h0    = strip * 2;

  const int ocg  = wid >> 2;          // 0..1 -> 64 oc each
  const int kp   = wid & 3;           // parity class
  const int ph   = kp >> 1, pw = kp & 1;
  const int lcol = lane & 15;         // pixel col (B) / oc row (A)
  const int lg   = lane >> 4;         // k-octet group

  // zero the wpair=32 pad column (wcol 64/65) of all 3 rows, both buffers
  if (tid < 48) {
    int bi = tid / 24, r2 = tid % 24;
    int k = r2 >> 3, g = r2 & 7;
    f32x4 z = {0.f, 0.f, 0.f, 0.f};
    *(f32x4*)((bi ? xb1 : xb0) + (k * 33 + 32) * 128 + g * 16) = z;
  }

  // chunk-invariant B-frag offsets; hh -> +2048 (wp+16: swizzle bits safe)
  int boff[4];
#pragma unroll
  for (int khkw = 0; khkw < 4; ++khkw) {
    int kh = khkw >> 1, kw = khkw & 1;
    int dy   = ph + kh;               // 0..2
    int wcol = 2 * lcol + pw + kw;
    int wp_  = wcol >> 1;
    boff[khkw] = ((dy * 33 + wp_) * 128 + (wcol & 1) * 64 + lg * 16) ^
                 ((wp_ & 7) << 4);
  }

  f32x4 acc[4][2];
#pragma unroll
  for (int m = 0; m < 4; ++m)
#pragma unroll
    for (int f = 0; f < 2; ++f) acc[m][f] = (f32x4){0.f, 0.f, 0.f, 0.f};

  const float* xbase = x + (size_t)n * C_IN * HW * HW;
  const int s_c  = tid >> 4;          // 0..31 channel within chunk
  const int s_w4 = tid & 15;          // float4 column
  f32x4 xr[3];
  v8bf  a_reg[4][4];

#define A_LOAD(QQ)                                                             \
  {                                                                            \
    _Pragma("unroll") for (int khkw = 0; khkw < 4; ++khkw) {                   \
      const __bf16* wp =                                                       \
          Wf + (((size_t)(kp * 4 + khkw) * 32 + (QQ) * 4 + lg) * 128 +        \
                ocg * 64 + lcol) * 8;                                          \
      _Pragma("unroll") for (int m = 0; m < 4; ++m)                            \
          a_reg[khkw][m] = *(const v8bf*)(wp + m * 128);                       \
    }                                                                          \
  }

#define LOADQ(QQ)                                                              \
  {                                                                            \
    const int cbase = (QQ) * 32;                                               \
    _Pragma("unroll") for (int k = 0; k < 3; ++k) {                            \
      int y = h0 + k;                                                          \
      if (y < HW)                                                              \
        xr[k] = *(const f32x4*)(xbase + ((size_t)(cbase + s_c) * HW + y) * HW +\
                                s_w4 * 4);                                     \
      else                                                                     \
        xr[k] = (f32x4){0.f, 0.f, 0.f, 0.f};                                   \
    }                                                                          \
  }

#define WRITEQ(QQ)                                                             \
  {                                                                            \
    char* xd = ((QQ) & 1) ? xb1 : xb0;                                         \
    _Pragma("unroll") for (int k = 0; k < 3; ++k) {                            \
      _Pragma("unroll") for (int j = 0; j < 4; ++j) {                          \
        int wcol = s_w4 * 4 + j;                                               \
        int wp_  = wcol >> 1;                                                  \
        int bo = ((k * 33 + wp_) * 128 + (wcol & 1) * 64 + s_c * 2) ^          \
                 ((wp_ & 7) << 4);                                             \
        *(__bf16*)(xd + bo) = (__bf16)xr[k][j];                                \
      }                                                                        \
    }                                                                          \
  }

  // prologue: fill buffer 0 with chunk 0
  LOADQ(0);
  WRITEQ(0);
  __syncthreads();

  for (int q = 0; q < 8; ++q) {
    A_LOAD(q);               // issued FIRST (vmcnt FIFO: keep x in flight)
    if (q < 7) LOADQ(q + 1);

    // ---- compute chunk q: 4 khkw x {2 ds_read_b128 + 8 MFMA} ----
    {
      const char* xsb = (q & 1) ? xb1 : xb0;
#pragma unroll
      for (int khkw = 0; khkw < 4; ++khkw) {
        v8bf b[2];
#pragma unroll
        for (int hh = 0; hh < 2; ++hh)
          b[hh] = *(const v8bf*)(xsb + boff[khkw] + hh * 2048);

        __builtin_amdgcn_s_setprio(1);
#pragma unroll
        for (int m = 0; m < 4; ++m)
#pragma unroll
          for (int f = 0; f < 2; ++f)
            acc[m][f] = __builtin_amdgcn_mfma_f32_16x16x32_bf16(
                a_reg[khkw][m], b[f], acc[m][f], 0, 0, 0);
        __builtin_amdgcn_s_setprio(0);
      }
    }

    if (q < 7) {
      WRITEQ(q + 1);     // other buffer, free since compute(q-1)
      __syncthreads();   // writes visible before compute(q+1)
    }
  }

  // ---- epilogue: D col=lane&15 (pixel), row=(lane>>4)*4+reg (oc) ----
  const int h = h0 + ph;
  if (h < OHW) {
#pragma unroll
    for (int m = 0; m < 4; ++m) {
#pragma unroll
      for (int hh = 0; hh < 2; ++hh) {
        const int w = 2 * (hh * 16 + lcol) + pw;
        f32x4 v = acc[m][hh];
        if (w < OHW) {
#pragma unroll
          for (int reg = 0; reg < 4; ++reg) {
            int oc = ocg * 64 + m * 16 + lg * 4 + reg;
            out[((size_t)(n * NOC + oc) * OHW + h) * OHW + w] =
                v[reg] + bias[oc * 4 + kp];
          }
        }
      }
    }
  }
#undef A_LOAD
#undef LOADQ
#undef WRITEQ
}

extern "C" void kernel_launch(void* const* d_in, const int* in_sizes, int n_in,
                              void* d_out, int out_size, void* d_ws, size_t ws_size,
                              hipStream_t stream) {
  const float* x      = (const float*)d_in[0];
  const float* weight = (const float*)d_in[1];
  const float* bias   = (const float*)d_in[2];
  float* out          = (float*)d_out;
  __bf16* Wf          = (__bf16*)d_ws;   // 1 MiB fragment-ordered weights

  wprep<<<512, 256, 0, stream>>>(weight, Wf);
  robin_main<<<dim3(32, 16), 512, 0, stream>>>(x, Wf, bias, out);
}

// Round 7
// 49.549 us; speedup vs baseline: 1.6074x; 1.6074x over previous
//
#include <hip/hip_runtime.h>

typedef __bf16 v8bf __attribute__((ext_vector_type(8)));
typedef float f32x4 __attribute__((ext_vector_type(4)));

#define C_IN 256
#define HW   64
#define OHW  63
#define NOC  128

// Wf: [kp(4)][khkw(4)][cblk(32)][oc(128)][j(8)] bf16, 1 MiB. Coalesced.
__global__ void wprep(const float* __restrict__ w, __bf16* __restrict__ Wf) {
  int f = blockIdx.x;                 // 512 filters
  int c = threadIdx.x;                // 256 channels
  f32x4 v = *(const f32x4*)(w + (size_t)f * 1024 + c * 4);  // 4 khkw taps
  int oc = f >> 2, kp = f & 3;
#pragma unroll
  for (int khkw = 0; khkw < 4; ++khkw)
    Wf[(((size_t)(kp * 4 + khkw) * 32 + (c >> 3)) * 128 + oc) * 8 + (c & 7)] =
        (__bf16)v[khkw];
}

// R5 structure + 2-deep register prefetch. Block: n x 4 out rows x 128 oc,
// 1024 thr (16 waves, 4/SIMD). wave = ocg(4: 32 oc) x kp(4).
// LDS x tile: [dy(5)][wpair(33)][par(2)][c(32)] bf16, XOR-swizzled, dbuf.
// Iter q: A(q)->regs first; x(q+2)->xr bank (2 deep); compute(q) waits only
// A (vmcnt keeps x in flight); WRITEQ(q+1) waits vmcnt(3) not 0; barrier.
__global__ __launch_bounds__(1024, 4) void robin_main(
    const float* __restrict__ x, const __bf16* __restrict__ Wf,
    const float* __restrict__ bias, float* __restrict__ out) {
  __shared__ __align__(16) __bf16 xs[2][5 * 33 * 64];   // 2 x 21120 B
  char* xb0 = (char*)xs[0];
  char* xb1 = (char*)xs[1];

  const int tid  = threadIdx.x;
  const int lane = tid & 63;
  const int wid  = tid >> 6;
  const int hb   = blockIdx.x;       // 16
  const int n    = blockIdx.y;       // 16
  const int h0   = hb * 4;

  const int ocg  = wid >> 2;         // 0..3 -> 32 oc each
  const int kp   = wid & 3;          // parity class
  const int ph   = kp >> 1, pw = kp & 1;
  const int lcol = lane & 15;        // pixel col (B) / oc row (A)
  const int lg   = lane >> 4;        // k-octet group

  // zero-fill wpair=32 pad rows (wcol 64/65), both buffers
  if (tid < 80) {
    int g  = tid & 7;
    int t2 = tid >> 3;
    int dy = t2 % 5, bi = t2 / 5;
    f32x4 z = {0.f, 0.f, 0.f, 0.f};
    *(f32x4*)((bi ? xb1 : xb0) + (dy * 33 + 32) * 128 + g * 16) = z;
  }

  // chunk-invariant B-frag base offsets (r -> +8448, hh -> +2048; deltas
  // touch bits >= 11, XOR swizzle touches bits 4..6 -> safe to add)
  int boff[4];
#pragma unroll
  for (int khkw = 0; khkw < 4; ++khkw) {
    int kh = khkw >> 1, kw = khkw & 1;
    int dy0  = ph + kh;
    int wcol = 2 * lcol + pw + kw;
    int wp_  = wcol >> 1;
    boff[khkw] = ((dy0 * 33 + wp_) * 128 + (wcol & 1) * 64 + lg * 16) ^
                 ((wp_ & 7) << 4);
  }

  f32x4 acc[2][4];
#pragma unroll
  for (int m = 0; m < 2; ++m)
#pragma unroll
    for (int f = 0; f < 4; ++f) acc[m][f] = (f32x4){0.f, 0.f, 0.f, 0.f};

  const float* xbase = x + (size_t)n * C_IN * HW * HW;
  f32x4 xrA[3], xrB[3];
  v8bf  a_reg[4][2];

#define A_LOAD(QQ)                                                             \
  {                                                                            \
    _Pragma("unroll") for (int khkw = 0; khkw < 4; ++khkw) {                   \
      const __bf16* wp =                                                       \
          Wf + (((size_t)(kp * 4 + khkw) * 32 + (QQ) * 4 + lg) * 128 +        \
                ocg * 32 + lcol) * 8;                                          \
      a_reg[khkw][0] = *(const v8bf*)wp;                                       \
      a_reg[khkw][1] = *(const v8bf*)(wp + 128);                               \
    }                                                                          \
  }

  // 2560 float4 units per chunk: unit v -> dy=v>>9, c=(v>>4)&31, w4=v&15
#define LOADQ(QQ, XR)                                                          \
  {                                                                            \
    const int cbase = (QQ) * 32;                                               \
    _Pragma("unroll") for (int k = 0; k < 3; ++k) {                            \
      int v = k * 1024 + tid;                                                  \
      if (v < 2560) {                                                          \
        int w4 = v & 15, c = (v >> 4) & 31, dy = v >> 9;                       \
        int y = h0 + dy;                                                       \
        if (y < HW)                                                            \
          XR[k] = *(const f32x4*)(xbase + ((size_t)(cbase + c) * HW + y) * HW +\
                                  w4 * 4);                                     \
        else                                                                   \
          XR[k] = (f32x4){0.f, 0.f, 0.f, 0.f};                                 \
      }                                                                        \
    }                                                                          \
  }

#define WRITEQ(QQ, XR)                                                         \
  {                                                                            \
    char* xd = ((QQ) & 1) ? xb1 : xb0;                                         \
    _Pragma("unroll") for (int k = 0; k < 3; ++k) {                            \
      int v = k * 1024 + tid;                                                  \
      if (v < 2560) {                                                          \
        int w4 = v & 15, c = (v >> 4) & 31, dy = v >> 9;                       \
        _Pragma("unroll") for (int j = 0; j < 4; ++j) {                        \
          int wcol = w4 * 4 + j;                                               \
          int wp_  = wcol >> 1;                                                \
          int bo = ((dy * 33 + wp_) * 128 + (wcol & 1) * 64 + c * 2) ^         \
                   ((wp_ & 7) << 4);                                           \
          *(__bf16*)(xd + bo) = (__bf16)XR[k][j];                              \
        }                                                                      \
      }                                                                        \
    }                                                                          \
  }

#define COMPUTE(QQ)                                                            \
  {                                                                            \
    const char* xsb = ((QQ) & 1) ? xb1 : xb0;                                  \
    _Pragma("unroll") for (int khkw = 0; khkw < 4; ++khkw) {                   \
      v8bf b[4];                                                               \
      _Pragma("unroll") for (int r = 0; r < 2; ++r)                            \
        _Pragma("unroll") for (int hh = 0; hh < 2; ++hh)                       \
          b[r * 2 + hh] =                                                      \
              *(const v8bf*)(xsb + boff[khkw] + r * 8448 + hh * 2048);         \
      _Pragma("unroll") for (int m = 0; m < 2; ++m)                            \
        _Pragma("unroll") for (int f = 0; f < 4; ++f)                          \
          acc[m][f] = __builtin_amdgcn_mfma_f32_16x16x32_bf16(                 \
              a_reg[khkw][m], b[f], acc[m][f], 0, 0, 0);                       \
    }                                                                          \
  }

  // iter q (even): x(q+2)->xrA, WRITE(q+1)<-xrB; odd: swapped.
#define ITER(QQ, XRL, XRW)                                                     \
  {                                                                            \
    A_LOAD(QQ);                /* issued FIRST: compute waits these only */    \
    if ((QQ) < 6) LOADQ((QQ) + 2, XRL);   /* 2-deep: consumed next iter */     \
    COMPUTE(QQ);                                                               \
    if ((QQ) < 7) {                                                            \
      WRITEQ((QQ) + 1, XRW);   /* data issued a full iteration ago */          \
      __syncthreads();                                                         \
    }                                                                          \
  }

  // prologue: x(0)->xrA, x(1)->xrB, stage chunk 0
  LOADQ(0, xrA);
  LOADQ(1, xrB);
  WRITEQ(0, xrA);
  __syncthreads();

  ITER(0, xrA, xrB);
  ITER(1, xrB, xrA);
  ITER(2, xrA, xrB);
  ITER(3, xrB, xrA);
  ITER(4, xrA, xrB);
  ITER(5, xrB, xrA);
  ITER(6, xrA, xrB);
  ITER(7, xrB, xrA);

  // ---- epilogue: D col=lane&15 (pixel), row=(lane>>4)*4+reg (oc) ----
#pragma unroll
  for (int m = 0; m < 2; ++m) {
#pragma unroll
    for (int r = 0; r < 2; ++r) {
      const int h = h0 + 2 * r + ph;
#pragma unroll
      for (int hh = 0; hh < 2; ++hh) {
        const int w = 2 * (hh * 16 + lcol) + pw;
        f32x4 v = acc[m][r * 2 + hh];
        if (h < OHW && w < OHW) {
#pragma unroll
          for (int reg = 0; reg < 4; ++reg) {
            int oc = ocg * 32 + m * 16 + lg * 4 + reg;
            out[((size_t)(n * NOC + oc) * OHW + h) * OHW + w] =
                v[reg] + bias[oc * 4 + kp];
          }
        }
      }
    }
  }
#undef A_LOAD
#undef LOADQ
#undef WRITEQ
#undef COMPUTE
#undef ITER
}

extern "C" void kernel_launch(void* const* d_in, const int* in_sizes, int n_in,
                              void* d_out, int out_size, void* d_ws, size_t ws_size,
                              hipStream_t stream) {
  const float* x      = (const float*)d_in[0];
  const float* weight = (const float*)d_in[1];
  const float* bias   = (const float*)d_in[2];
  float* out          = (float*)d_out;
  __bf16* Wf          = (__bf16*)d_ws;   // 1 MiB fragment-ordered weights

  wprep<<<512, 256, 0, stream>>>(weight, Wf);
  robin_main<<<dim3(16, 16), 1024, 0, stream>>>(x, Wf, bias, out);
}